// Round 4
// baseline (711.410 us; speedup 1.0000x reference)
//
#include <hip/hip_runtime.h>
#include <hip/hip_bf16.h>
#include <math.h>

typedef __attribute__((ext_vector_type(8))) short s16x8;
typedef __attribute__((ext_vector_type(4))) float f32x4;

static __device__ __forceinline__ float bf2f(unsigned short u){
    unsigned int x = ((unsigned int)u) << 16; float f; __builtin_memcpy(&f,&x,4); return f;
}
static __device__ __forceinline__ unsigned short f2bf(float f){
    unsigned int x; __builtin_memcpy(&x,&f,4);
    unsigned int r = (x + 0x7FFFu + ((x>>16)&1u)) >> 16; return (unsigned short)r;
}

static __device__ __forceinline__ void stage16(const void* g, void* l){
    __builtin_amdgcn_global_load_lds((const __attribute__((address_space(1))) unsigned int*)g,
                                     (__attribute__((address_space(3))) unsigned int*)l, 16, 0, 0);
}

// ---------------- sizes ----------------
// N=64, C=128, T=128, V=25, S=3, K=7
// JN = 3200, NTV = 204800, PADROW = 3350, K-dim = (s,ci)x k = 384*7 = 2688

// ---------------- prep: consts, ffA bf16, wbpart, G zero, ypad halo zero ----------------
__global__ void prep_kernel(const float* __restrict__ out_w, const float* __restrict__ ff_w,
                            const float* __restrict__ v_b,
                            const float* __restrict__ out_b, const float* __restrict__ out_g,
                            const float* __restrict__ out_be, const float* __restrict__ out_m,
                            const float* __restrict__ out_v,
                            const float* __restrict__ ff_b, const float* __restrict__ ff_g,
                            const float* __restrict__ ff_be, const float* __restrict__ ff_m,
                            const float* __restrict__ ff_v,
                            float* __restrict__ G, float* __restrict__ consts,
                            unsigned short* __restrict__ ffA, unsigned short* __restrict__ ypad,
                            float* __restrict__ wbpart)
{
    int stride = gridDim.x*blockDim.x;
    int i0 = blockIdx.x*blockDim.x + threadIdx.x;
    for (int i=i0; i<40000; i+=stride) G[i] = 0.f;
    for (int i=i0; i<16384; i+=stride) ffA[i] = f2bf(ff_w[i]);
    for (int i=i0; i<128; i+=stride){
        float inv  = out_g[i]/sqrtf(out_v[i]+1e-5f);
        consts[i]       = inv;
        consts[128+i]   = out_b[i]*inv + out_be[i] - out_m[i]*inv;
        float invf = ff_g[i]/sqrtf(ff_v[i]+1e-5f);
        consts[256+i]   = invf;
        consts[384+i]   = ff_b[i]*invf + ff_be[i] - ff_m[i]*invf;
    }
    // wbpart[o][s][tc] = sum_{k in range(tc)} sum_c out_w[o,(s,c),k] * v_b[c]
    // tc: 0,1,2 -> t=0,1,2 (kmin=3-tc); 3 -> interior; 4,5,6 -> t=125,126,127 (kmax=10-tc)
    for (int i=i0; i<2688; i+=stride){
        int o = i/21, rem = i%21, s = rem/7, tc = rem%7;
        int kmin = (tc<3) ? (3-tc) : 0;
        int kmax = (tc>3) ? (10-tc) : 7;
        float acc = 0.f;
        for (int c=0; c<128; ++c){
            const float* wp = out_w + (size_t)(o*384 + s*128 + c)*7;
            float vb = v_b[c];
            for (int k=kmin; k<kmax; ++k) acc += wp[k]*vb;
        }
        wbpart[i] = acc;
    }
    // zero the temporal halo pads of Ypad: positions [0,75) and [3275,3350) per (n)
    for (int i=i0; i<3686400; i+=stride){
        int n2 = i/57600, r2 = i%57600;
        int pp = r2/384, sc = r2%384;
        int ppos = (pp < 75) ? pp : (3200 + pp);   // -> [3275,3350)
        ypad[(size_t)(n2*3350 + ppos)*384 + sc] = 0;
    }
}

// ---------------- wfold: Wr[o][(s,ci),k packed] = sum_c out_w[o,(s,c),k] * v_w[c,ci] ----------------
// packed layout: kb = (sci/32)*7 + k, j = sci%32  ->  Wr[o*2688 + kb*32 + j]
__global__ __launch_bounds__(384) void wfold_kernel(const float* __restrict__ out_w,
                                                    const float* __restrict__ v_w,
                                                    unsigned short* __restrict__ Wr){
    __shared__ float owl[384];
    int o = blockIdx.x / 7, k = blockIdx.x % 7;
    int tid = threadIdx.x;              // sci = s*128 + ci
    owl[tid] = out_w[(size_t)(o*384 + tid)*7 + k];
    __syncthreads();
    int s = tid >> 7, ci = tid & 127;
    const float* ow = owl + s*128;
    float acc = 0.f;
    #pragma unroll 8
    for (int c=0; c<128; ++c) acc += ow[c] * v_w[c*128 + ci];
    int kb = (tid>>5)*7 + k, jj = tid & 31;
    Wr[(size_t)o*2688 + kb*32 + jj] = f2bf(acc);
}

// ---------------- x transpose: x[n][c][jn] fp32 -> xbt[n][jn][c] bf16 ----------------
__global__ __launch_bounds__(256) void xt_kernel(const float* __restrict__ x, unsigned short* __restrict__ xbt){
    __shared__ float tile[32][33];
    int bid = blockIdx.x;
    int jb = bid % 100; int cb = (bid/100) & 3; int n = bid/400;
    int tx = threadIdx.x & 31, ty = threadIdx.x >> 5;
    size_t xbase = (size_t)n*409600;
    #pragma unroll
    for (int r=ty; r<32; r+=8)
        tile[r][tx] = x[xbase + (size_t)(cb*32+r)*3200 + jb*32 + tx];
    __syncthreads();
    #pragma unroll
    for (int r=ty; r<32; r+=8)
        xbt[xbase + (size_t)(jb*32+r)*128 + cb*32 + tx] = f2bf(tile[tx][r]);
}

// ---------------- gram: G[n][u][v] = sum_{c,t} (x+pe)[c,t,u]*(x+pe)[c,t,v] ----------------
__global__ __launch_bounds__(640) void gram_kernel(const float* __restrict__ x, float* __restrict__ G){
    __shared__ float yl[128][26];
    int bid = blockIdx.x; int n = bid >> 4; int chunk = bid & 15;
    int tid = threadIdx.x;
    int u = tid/25, vv = tid%25;
    float accv = 0.f;
    for (int g=0; g<8; ++g){
        int c = chunk*8 + g;
        float freq = expf(-(float)(c & ~1) * (9.210340371976184f/128.f));
        __syncthreads();
        for (int e=tid; e<3200; e+=640){
            int v = e % 25;
            float ang = (float)v * freq;
            float pe = (c & 1) ? cosf(ang) : sinf(ang);
            yl[e/25][v] = x[(size_t)n*409600 + (size_t)c*3200 + e] + pe;
        }
        __syncthreads();
        if (tid < 625){
            #pragma unroll 4
            for (int t=0; t<128; ++t) accv += yl[t][u]*yl[t][vv];
        }
    }
    if (tid < 625) atomicAdd(&G[n*625 + tid], accv);
}

// ---------------- attention: global max + sparsemax (+asum) ----------------
__global__ __launch_bounds__(1024) void attn_kernel(const float* __restrict__ G, const float* __restrict__ theta,
                                                    const float* __restrict__ atts, const float* __restrict__ alphas,
                                                    float* __restrict__ att, float* __restrict__ asum){
    __shared__ float red[1024];
    int tid = threadIdx.x;
    float mx = 0.f;
    for (int idx=tid; idx<40000; idx+=1024){
        int n = idx/625, r = idx%625, u2 = r/25, v2 = r%25;
        const float* Gn = G + n*625;
        float d2v = fmaxf(Gn[u2*26] + Gn[v2*26] - 2.f*Gn[u2*25+v2], 0.f);
        mx = fmaxf(mx, d2v);
    }
    red[tid] = mx; __syncthreads();
    for (int s2=512; s2>0; s2>>=1){ if (tid < s2) red[tid] = fmaxf(red[tid], red[tid+s2]); __syncthreads(); }
    float inv = 1.f/red[0];
    for (int col=tid; col<4800; col+=1024){
        int n = col/75, r = col%75, s = r/25, vc = r%25;
        const float* Gn = G + n*625;
        float et = expf(theta[s]);
        float al = alphas[s];
        float gvv = Gn[vc*26];
        float z[25];
        #pragma unroll
        for (int u2=0; u2<25; ++u2){
            float d2v = fmaxf(Gn[u2*26] + gvv - 2.f*Gn[u2*25+vc], 0.f);
            z[u2] = expf(-et*d2v*inv);
        }
        float zm = z[0];
        #pragma unroll
        for (int u2=1; u2<25; ++u2) zm = fmaxf(zm, z[u2]);
        float lo = zm - 1.f, hi = zm;
        for (int it=0; it<30; ++it){
            float mid = 0.5f*(lo+hi);
            float f = 0.f;
            #pragma unroll
            for (int u2=0; u2<25; ++u2) f += fmaxf(z[u2]-mid, 0.f);
            if (f >= 1.f) lo = mid; else hi = mid;
        }
        float ssum = 0.f; int kcnt = 0;
        #pragma unroll
        for (int u2=0; u2<25; ++u2){ if (z[u2] > lo){ ssum += z[u2]; kcnt++; } }
        float tau = (ssum - 1.f)/(float)kcnt;
        float as_ = 0.f;
        #pragma unroll
        for (int u2=0; u2<25; ++u2){
            float av = atts[s*625 + u2*25 + vc] + fmaxf(z[u2]-tau, 0.f)*al;
            att[n*1875 + s*625 + u2*25 + vc] = av;
            as_ += av;
        }
        asum[n*75 + s*25 + vc] = as_;
    }
}

// ---------------- aggregation: xagg[n,(s,ci),t,v] = sum_u x[ci,t,u]*att[n,s,u,v] -> Ypad ----------------
__global__ __launch_bounds__(128) void agg_kernel(const unsigned short* __restrict__ xbt,
                                                  const float* __restrict__ att,
                                                  unsigned short* __restrict__ ypad){
    __shared__ float attl[1875];
    __shared__ unsigned short vxl[3200];   // [25][128]
    int bid = blockIdx.x; int n = bid >> 7; int t = bid & 127;
    int tid = threadIdx.x;  // = ci
    for (int i=tid; i<1875; i+=128) attl[i] = att[n*1875 + i];
    {
        const unsigned int* src = (const unsigned int*)(xbt + ((size_t)(n*3200 + t*25))*128);
        unsigned int* dst = (unsigned int*)vxl;
        for (int i=tid; i<1600; i+=128) dst[i] = src[i];
    }
    __syncthreads();
    float p[25];
    #pragma unroll
    for (int u2=0; u2<25; ++u2) p[u2] = bf2f(vxl[u2*128 + tid]);
    size_t obase = ((size_t)(n*3350 + 75 + t*25))*384 + tid;
    #pragma unroll
    for (int s=0; s<3; ++s){
        #pragma unroll 5
        for (int v2=0; v2<25; ++v2){
            float acc2 = 0.f;
            #pragma unroll
            for (int u2=0; u2<25; ++u2) acc2 += p[u2]*attl[s*625 + u2*25 + v2];
            ypad[obase + (size_t)v2*384 + s*128] = f2bf(acc2);
        }
    }
}

// ---------------- fused conv+ff GEMM, 128x128 tile, BK=32, 3-deep counted-vmcnt pipeline ----------------
// conv: acc = Wr(Wfold packed) @ Ypad, + BN + v_b-term + x-residual + leaky -> LDS-transposed tile
// ff:   acc2 = ffA @ tile, + BN + x-residual + leaky -> out fp32
__global__ __launch_bounds__(256,3) void gemm_fused(const unsigned short* __restrict__ Amat,
                                                    const unsigned short* __restrict__ Bsrc,
                                                    const float* __restrict__ xin,
                                                    const float* __restrict__ consts,
                                                    const unsigned short* __restrict__ ffA,
                                                    const float* __restrict__ wbpart,
                                                    const float* __restrict__ asum,
                                                    float* __restrict__ outf)
{
    constexpr int KTOT = 2688, NKB = 84;
    __shared__ unsigned short smem[24576];   // 3 x (A 128x32 + B 128x32) = 48 KB; reused by epilogue

    const int tid = threadIdx.x;
    const int bid = blockIdx.x;
    const int n   = bid/25;
    const int jn0 = (bid%25)*128;

    const int lane = tid & 63, wv = tid >> 6;
    const int wm = wv >> 1, wn = wv & 1;
    const int lr = lane & 15, lg = lane >> 4;
    const int swz = (lg ^ ((lr>>1)&3)) << 3;

    const int ga0 = tid, ga1 = 256 + tid;
    const int ra0 = ga0>>2, ra1 = ga1>>2;
    const int ca0 = ((ga0&3) ^ ((ra0>>1)&3))*8;
    const int ca1 = ((ga1&3) ^ ((ra1>>1)&3))*8;

    auto stage = [&](int kb, int buf){
        unsigned short* dst = smem + buf*8192;
        stage16(Amat + (size_t)ra0*KTOT + kb*32 + ca0, dst + ga0*8);
        stage16(Amat + (size_t)ra1*KTOT + kb*32 + ca1, dst + ga1*8);
        int k = kb%7, scb = (kb/7)*32;
        const unsigned short* bb = Bsrc + ((size_t)(n*3350 + jn0 + 25*k))*384 + scb;
        stage16(bb + (size_t)ra0*384 + ca0, dst + 4096 + ga0*8);
        stage16(bb + (size_t)ra1*384 + ca1, dst + 4096 + ga1*8);
    };

    f32x4 acc[4][4];
    #pragma unroll
    for (int a=0;a<4;a++)
        #pragma unroll
        for (int b=0;b<4;b++) acc[a][b] = (f32x4){0.f,0.f,0.f,0.f};

    stage(0, 0);
    stage(1, 1);
    int bufc = 0, bufp = 2;
    for (int kb=0; kb<NKB; ++kb){
        if (kb < NKB-1) asm volatile("s_waitcnt vmcnt(4)" ::: "memory");
        else            asm volatile("s_waitcnt vmcnt(0)" ::: "memory");
        __builtin_amdgcn_s_barrier();
        asm volatile("" ::: "memory");
        const unsigned short* sA = smem + bufc*8192;
        const unsigned short* sB = sA + 4096;
        s16x8 a[4], b[4];
        #pragma unroll
        for (int mf=0; mf<4; ++mf) a[mf] = *(const s16x8*)&sA[(wm*64+mf*16+lr)*32 + swz];
        #pragma unroll
        for (int nf=0; nf<4; ++nf) b[nf] = *(const s16x8*)&sB[(wn*64+nf*16+lr)*32 + swz];
        if (kb+2 < NKB) stage(kb+2, bufp);
        __builtin_amdgcn_s_setprio(1);
        #pragma unroll
        for (int mf=0; mf<4; ++mf)
            #pragma unroll
            for (int nf=0; nf<4; ++nf)
                acc[mf][nf] = __builtin_amdgcn_mfma_f32_16x16x32_bf16(a[mf], b[nf], acc[mf][nf], 0, 0, 0);
        __builtin_amdgcn_s_setprio(0);
        bufc = (bufc==2) ? 0 : bufc+1;
        bufp = (bufp==2) ? 0 : bufp+1;
    }
    __syncthreads();

    // stage wbpart + asum into smem tail (bytes [34816, 45868) -- above the 34.8KB transpose tile)
    float* wbl = (float*)(smem + 17408);   // 2688 floats
    float* asl = wbl + 2688;               // 75 floats
    for (int i=tid; i<2688; i+=256) wbl[i] = wbpart[i];
    for (int i=tid; i<75;   i+=256) asl[i] = asum[n*75 + i];
    __syncthreads();

    // epilogue 1: conv BN + v_b-term + x residual + leaky -> transposed bf16 tile [cj][o]
    #pragma unroll
    for (int nf=0; nf<4; ++nf){
        int cj = wn*64 + nf*16 + lr;
        int j  = jn0 + cj;
        int t  = j/25, v = j - t*25;
        int tc = (t<3) ? t : ((t>124) ? (t-121) : 3);
        float a0 = asl[v], a1 = asl[25+v], a2 = asl[50+v];
        #pragma unroll
        for (int mf=0; mf<4; ++mf)
            #pragma unroll
            for (int r=0; r<4; ++r){
                int m = wm*64 + mf*16 + lg*4 + r;
                float b2v = wbl[m*21+tc]*a0 + wbl[m*21+7+tc]*a1 + wbl[m*21+14+tc]*a2;
                float val = acc[mf][nf][r]*consts[m] + consts[128+m] + b2v
                          + xin[(size_t)n*409600 + (size_t)m*3200 + j];
                val = (val >= 0.f) ? val : 0.1f*val;
                smem[cj*136 + m] = f2bf(val);
            }
    }
    __syncthreads();

    // GEMM 2: out2 = ffA @ tile  (K = 128 over conv channels)
    f32x4 acc2[4][4];
    #pragma unroll
    for (int a=0;a<4;a++)
        #pragma unroll
        for (int b=0;b<4;b++) acc2[a][b] = (f32x4){0.f,0.f,0.f,0.f};
    #pragma unroll
    for (int kb2=0; kb2<4; ++kb2){
        s16x8 a2[4], b2[4];
        #pragma unroll
        for (int mf=0; mf<4; ++mf)
            a2[mf] = *(const s16x8*)&ffA[(size_t)(wm*64+mf*16+lr)*128 + kb2*32 + lg*8];
        #pragma unroll
        for (int nf=0; nf<4; ++nf)
            b2[nf] = *(const s16x8*)&smem[(wn*64+nf*16+lr)*136 + kb2*32 + lg*8];
        #pragma unroll
        for (int mf=0; mf<4; ++mf)
            #pragma unroll
            for (int nf=0; nf<4; ++nf)
                acc2[mf][nf] = __builtin_amdgcn_mfma_f32_16x16x32_bf16(a2[mf], b2[nf], acc2[mf][nf], 0, 0, 0);
    }

    // epilogue 2: ff BN + x residual + leaky -> out fp32
    #pragma unroll
    for (int mf=0; mf<4; ++mf)
        #pragma unroll
        for (int r=0; r<4; ++r){
            int co = wm*64 + mf*16 + lg*4 + r;
            float sc2 = consts[256+co], bi2 = consts[384+co];
            #pragma unroll
            for (int nf=0; nf<4; ++nf){
                int cj = wn*64 + nf*16 + lr;
                size_t idx = (size_t)n*409600 + (size_t)co*3200 + jn0 + cj;
                float val = acc2[mf][nf][r]*sc2 + bi2 + xin[idx];
                val = (val >= 0.f) ? val : 0.1f*val;
                outf[idx] = val;
            }
        }
}

extern "C" void kernel_launch(void* const* d_in, const int* in_sizes, int n_in,
                              void* d_out, int out_size, void* d_ws, size_t ws_size,
                              hipStream_t stream) {
    const float* x      = (const float*)d_in[0];
    const float* theta  = (const float*)d_in[1];
    const float* atts   = (const float*)d_in[2];
    const float* alphas = (const float*)d_in[3];
    const float* v_w    = (const float*)d_in[4];
    const float* v_b    = (const float*)d_in[5];
    const float* out_w  = (const float*)d_in[6];
    const float* out_b  = (const float*)d_in[7];
    const float* out_g  = (const float*)d_in[8];
    const float* out_be = (const float*)d_in[9];
    const float* out_m  = (const float*)d_in[10];
    const float* out_v  = (const float*)d_in[11];
    const float* ff_w   = (const float*)d_in[12];
    const float* ff_b   = (const float*)d_in[13];
    const float* ff_g   = (const float*)d_in[14];
    const float* ff_be  = (const float*)d_in[15];
    const float* ff_m   = (const float*)d_in[16];
    const float* ff_v   = (const float*)d_in[17];
    float* out = (float*)d_out;

    char* w = (char*)d_ws;
    size_t off = 0;
    auto alloc = [&](size_t b){ size_t r = off; off += (b + 1023) & ~(size_t)1023; return r; };
    float*          G      = (float*)         (w + alloc(160000));      // 64*625 f32
    float*          attbuf = (float*)         (w + alloc(480000));      // 64*1875 f32
    float*          asumb  = (float*)         (w + alloc(19200));       // 64*75 f32
    float*          consts = (float*)         (w + alloc(2048));        // 512 f32
    float*          wbpart = (float*)         (w + alloc(10752));       // 128*3*7 f32
    unsigned short* Wr     = (unsigned short*)(w + alloc(688128));      // Wfold packed, 128*2688 bf16
    unsigned short* ffA    = (unsigned short*)(w + alloc(32768));
    unsigned short* xbt    = (unsigned short*)(w + alloc(52428800));    // [n][tv][c] bf16
    unsigned short* ypad   = (unsigned short*)(w + alloc(164659200));   // [n][3350][384] bf16

    prep_kernel<<<2048,256,0,stream>>>(out_w, ff_w, v_b, out_b, out_g, out_be, out_m, out_v,
                                       ff_b, ff_g, ff_be, ff_m, ff_v,
                                       G, consts, ffA, ypad, wbpart);
    wfold_kernel<<<896,384,0,stream>>>(out_w, v_w, Wr);
    xt_kernel<<<25600,256,0,stream>>>(x, xbt);
    gram_kernel<<<1024,640,0,stream>>>(x, G);
    attn_kernel<<<1,1024,0,stream>>>(G, theta, atts, alphas, attbuf, asumb);
    agg_kernel<<<8192,128,0,stream>>>(xbt, attbuf, ypad);
    gemm_fused<<<1600,256,0,stream>>>(Wr, ypad, x, consts, ffA, wbpart, asumb, out);
}

// Round 5
// 702.623 us; speedup vs baseline: 1.0125x; 1.0125x over previous
//
#include <hip/hip_runtime.h>
#include <hip/hip_bf16.h>
#include <math.h>

typedef __attribute__((ext_vector_type(8))) short s16x8;
typedef __attribute__((ext_vector_type(4))) float f32x4;

static __device__ __forceinline__ float bf2f(unsigned short u){
    unsigned int x = ((unsigned int)u) << 16; float f; __builtin_memcpy(&f,&x,4); return f;
}
static __device__ __forceinline__ unsigned short f2bf(float f){
    unsigned int x; __builtin_memcpy(&x,&f,4);
    unsigned int r = (x + 0x7FFFu + ((x>>16)&1u)) >> 16; return (unsigned short)r;
}

static __device__ __forceinline__ void stage16(const void* g, void* l){
    __builtin_amdgcn_global_load_lds((const __attribute__((address_space(1))) unsigned int*)g,
                                     (__attribute__((address_space(3))) unsigned int*)l, 16, 0, 0);
}

// ---------------- sizes ----------------
// N=64, C=128, T=128, V=25, S=3, K=7
// JN = 3200, NTV = 204800, PADROW = 3350, K-dim = 384*7 = 2688

// ---------------- prep: consts, ffA bf16, wbpart, peb, TPg, ypad halo zero ----------------
__global__ void prep_kernel(const float* __restrict__ out_w, const float* __restrict__ ff_w,
                            const float* __restrict__ v_b,
                            const float* __restrict__ out_b, const float* __restrict__ out_g,
                            const float* __restrict__ out_be, const float* __restrict__ out_m,
                            const float* __restrict__ out_v,
                            const float* __restrict__ ff_b, const float* __restrict__ ff_g,
                            const float* __restrict__ ff_be, const float* __restrict__ ff_m,
                            const float* __restrict__ ff_v,
                            float* __restrict__ consts,
                            unsigned short* __restrict__ ffA, unsigned short* __restrict__ ypad,
                            float* __restrict__ wbpart,
                            float* __restrict__ pebg, float* __restrict__ TPgb)
{
    int stride = gridDim.x*blockDim.x;
    int i0 = blockIdx.x*blockDim.x + threadIdx.x;
    const float KLN = 9.210340371976184f/128.f;   // ln(1e4)/C
    for (int i=i0; i<16384; i+=stride) ffA[i] = f2bf(ff_w[i]);
    for (int i=i0; i<128; i+=stride){
        float inv  = out_g[i]/sqrtf(out_v[i]+1e-5f);
        consts[i]       = inv;
        consts[128+i]   = out_b[i]*inv + out_be[i] - out_m[i]*inv;
        float invf = ff_g[i]/sqrtf(ff_v[i]+1e-5f);
        consts[256+i]   = invf;
        consts[384+i]   = ff_b[i]*invf + ff_be[i] - ff_m[i]*invf;
    }
    // pe table: pebg[v*128 + c] = pe value for channel c at joint v
    for (int i=i0; i<3200; i+=stride){
        int v = i >> 7, c = i & 127;
        float freq = expf(-(float)(c & ~1) * KLN);
        float ang = (float)v * freq;
        pebg[i] = (c & 1) ? cosf(ang) : sinf(ang);
    }
    // TPgb[u*25+v] = T * sum_c pe[c][u]*pe[c][v]
    for (int i=i0; i<625; i+=stride){
        int u = i/25, v = i%25;
        float acc = 0.f;
        for (int c=0; c<128; ++c){
            float freq = expf(-(float)(c & ~1) * KLN);
            float pu = (c & 1) ? cosf((float)u*freq) : sinf((float)u*freq);
            float pv = (c & 1) ? cosf((float)v*freq) : sinf((float)v*freq);
            acc += pu*pv;
        }
        TPgb[i] = 128.f*acc;
    }
    // wbpart[o][s][tc] = sum_{k in range(tc)} sum_c out_w[o,(s,c),k] * v_b[c]
    for (int i=i0; i<2688; i+=stride){
        int o = i/21, rem = i%21, s = rem/7, tc = rem%7;
        int kmin = (tc<3) ? (3-tc) : 0;
        int kmax = (tc>3) ? (10-tc) : 7;
        float acc = 0.f;
        for (int c=0; c<128; ++c){
            const float* wp = out_w + (size_t)(o*384 + s*128 + c)*7;
            float vb = v_b[c];
            for (int k=kmin; k<kmax; ++k) acc += wp[k]*vb;
        }
        wbpart[i] = acc;
    }
    // zero the temporal halo pads of Ypad
    for (int i=i0; i<3686400; i+=stride){
        int n2 = i/57600, r2 = i%57600;
        int pp = r2/384, sc = r2%384;
        int ppos = (pp < 75) ? pp : (3200 + pp);
        ypad[(size_t)(n2*3350 + ppos)*384 + sc] = 0;
    }
}

// ---------------- wfold: Wr[o][(s,ci),k packed] = sum_c out_w[o,(s,c),k] * v_w[c,ci] ----------------
__global__ __launch_bounds__(384) void wfold_kernel(const float* __restrict__ out_w,
                                                    const float* __restrict__ v_w,
                                                    unsigned short* __restrict__ Wr){
    __shared__ float owl[384];
    int o = blockIdx.x / 7, k = blockIdx.x % 7;
    int tid = threadIdx.x;
    owl[tid] = out_w[(size_t)(o*384 + tid)*7 + k];
    __syncthreads();
    int s = tid >> 7, ci = tid & 127;
    const float* ow = owl + s*128;
    float acc = 0.f;
    #pragma unroll 8
    for (int c=0; c<128; ++c) acc += ow[c] * v_w[c*128 + ci];
    int kb = (tid>>5)*7 + k, jj = tid & 31;
    Wr[(size_t)o*2688 + kb*32 + jj] = f2bf(acc);
}

// ---------------- x transpose: x[n][c][jn] fp32 -> xbt[n][jn][c] bf16, 64x64 tiles ----------------
__global__ __launch_bounds__(256) void xt_kernel(const float* __restrict__ x, unsigned short* __restrict__ xbt){
    __shared__ float tile[64][65];
    int bid = blockIdx.x;
    int jb = bid % 50; int cb = (bid/50) & 1; int n = bid/100;
    int lane = threadIdx.x & 63, wv = threadIdx.x >> 6;
    size_t xbase = (size_t)n*409600;
    #pragma unroll
    for (int r=wv; r<64; r+=4)
        tile[r][lane] = x[xbase + (size_t)(cb*64+r)*3200 + jb*64 + lane];
    __syncthreads();
    #pragma unroll
    for (int j=wv; j<64; j+=4)
        xbt[xbase + (size_t)(jb*64+j)*128 + cb*64 + lane] = f2bf(tile[lane][j]);
}

// ---------------- gram via MFMA: G[n][u][v] = Gx + corr(pe) ----------------
// Gx[u][v] = sum_{t,c} xbt[t*25+u][c]*xbt[t*25+v][c]  (bf16 MFMA, fp32 acc)
// corr[u][v] = sum_c sx[u][c]*pe[v][c] + sx[v][c]*pe[u][c] + T*Pg[u][v]
__global__ __launch_bounds__(256) void gram_mfma(const unsigned short* __restrict__ xbt,
                                                 const float* __restrict__ pebg,
                                                 const float* __restrict__ TPgb,
                                                 float* __restrict__ G){
    __shared__ float sxl[25][129];
    __shared__ float pebl[25][129];
    __shared__ float glx[4][32][32];
    int n = blockIdx.x, tid = threadIdx.x;
    const unsigned short* xb = xbt + (size_t)n*409600;

    // phase A: sx[u][c] = sum_t xbt[t*25+u][c]
    int c = tid & 127, th = tid >> 7;
    float a[25];
    #pragma unroll
    for (int u=0; u<25; ++u) a[u] = 0.f;
    for (int tt=0; tt<64; ++tt){
        const unsigned short* row = xb + (size_t)(th*64+tt)*3200 + c;
        #pragma unroll
        for (int u=0; u<25; ++u) a[u] += bf2f(row[u*128]);
    }
    float* tmp = &glx[0][0][0];
    if (th){
        #pragma unroll
        for (int u=0; u<25; ++u) tmp[u*128+c] = a[u];
    }
    __syncthreads();
    if (!th){
        #pragma unroll
        for (int u=0; u<25; ++u) sxl[u][c] = a[u] + tmp[u*128+c];
    }
    for (int i=tid; i<3200; i+=256) pebl[i>>7][i&127] = pebg[i];
    __syncthreads();

    // phase B: Gx via MFMA; wave w covers t = 4*tt + w
    int lane = tid & 63, w = tid >> 6;
    int lr = lane & 15, lg = lane >> 4;
    f32x4 acc[2][2];
    #pragma unroll
    for (int i2=0;i2<2;i2++)
        #pragma unroll
        for (int j2=0;j2<2;j2++) acc[i2][j2] = (f32x4){0.f,0.f,0.f,0.f};
    for (int tt=0; tt<32; ++tt){
        int t = tt*4 + w;
        const unsigned short* tb = xb + (size_t)t*3200;
        #pragma unroll
        for (int kc=0; kc<4; ++kc){
            s16x8 f0 = *(const s16x8*)(tb + (size_t)(lr)*128      + kc*32 + lg*8);
            s16x8 f1 = *(const s16x8*)(tb + (size_t)(16+lr)*128   + kc*32 + lg*8);
            acc[0][0] = __builtin_amdgcn_mfma_f32_16x16x32_bf16(f0, f0, acc[0][0], 0,0,0);
            acc[0][1] = __builtin_amdgcn_mfma_f32_16x16x32_bf16(f0, f1, acc[0][1], 0,0,0);
            acc[1][0] = __builtin_amdgcn_mfma_f32_16x16x32_bf16(f1, f0, acc[1][0], 0,0,0);
            acc[1][1] = __builtin_amdgcn_mfma_f32_16x16x32_bf16(f1, f1, acc[1][1], 0,0,0);
        }
    }
    __syncthreads();   // glx temp (phase A) fully consumed
    #pragma unroll
    for (int mh=0; mh<2; ++mh)
        #pragma unroll
        for (int nh=0; nh<2; ++nh)
            #pragma unroll
            for (int r=0; r<4; ++r)
                glx[w][mh*16 + lg*4 + r][nh*16 + lr] = acc[mh][nh][r];
    __syncthreads();

    // phase C: reduce waves + pe correction
    for (int idx=tid; idx<625; idx+=256){
        int u = idx/25, v = idx%25;
        float gx = glx[0][u][v] + glx[1][u][v] + glx[2][u][v] + glx[3][u][v];
        float cr = TPgb[idx];
        #pragma unroll 4
        for (int cc=0; cc<128; ++cc)
            cr += sxl[u][cc]*pebl[v][cc] + sxl[v][cc]*pebl[u][cc];
        G[n*625 + idx] = gx + cr;
    }
}

// ---------------- attention: global max + sparsemax (+asum) ----------------
__global__ __launch_bounds__(1024) void attn_kernel(const float* __restrict__ G, const float* __restrict__ theta,
                                                    const float* __restrict__ atts, const float* __restrict__ alphas,
                                                    float* __restrict__ att, float* __restrict__ asum){
    __shared__ float red[1024];
    int tid = threadIdx.x;
    float mx = 0.f;
    for (int idx=tid; idx<40000; idx+=1024){
        int n = idx/625, r = idx%625, u2 = r/25, v2 = r%25;
        const float* Gn = G + n*625;
        float d2v = fmaxf(Gn[u2*26] + Gn[v2*26] - 2.f*Gn[u2*25+v2], 0.f);
        mx = fmaxf(mx, d2v);
    }
    red[tid] = mx; __syncthreads();
    for (int s2=512; s2>0; s2>>=1){ if (tid < s2) red[tid] = fmaxf(red[tid], red[tid+s2]); __syncthreads(); }
    float inv = 1.f/red[0];
    for (int col=tid; col<4800; col+=1024){
        int n = col/75, r = col%75, s = r/25, vc = r%25;
        const float* Gn = G + n*625;
        float et = expf(theta[s]);
        float al = alphas[s];
        float gvv = Gn[vc*26];
        float z[25];
        #pragma unroll
        for (int u2=0; u2<25; ++u2){
            float d2v = fmaxf(Gn[u2*26] + gvv - 2.f*Gn[u2*25+vc], 0.f);
            z[u2] = expf(-et*d2v*inv);
        }
        float zm = z[0];
        #pragma unroll
        for (int u2=1; u2<25; ++u2) zm = fmaxf(zm, z[u2]);
        float lo = zm - 1.f, hi = zm;
        for (int it=0; it<30; ++it){
            float mid = 0.5f*(lo+hi);
            float f = 0.f;
            #pragma unroll
            for (int u2=0; u2<25; ++u2) f += fmaxf(z[u2]-mid, 0.f);
            if (f >= 1.f) lo = mid; else hi = mid;
        }
        float ssum = 0.f; int kcnt = 0;
        #pragma unroll
        for (int u2=0; u2<25; ++u2){ if (z[u2] > lo){ ssum += z[u2]; kcnt++; } }
        float tau = (ssum - 1.f)/(float)kcnt;
        float as_ = 0.f;
        #pragma unroll
        for (int u2=0; u2<25; ++u2){
            float av = atts[s*625 + u2*25 + vc] + fmaxf(z[u2]-tau, 0.f)*al;
            att[n*1875 + s*625 + u2*25 + vc] = av;
            as_ += av;
        }
        asum[n*75 + s*25 + vc] = as_;
    }
}

// ---------------- aggregation: xagg[n,(s,ci),t,v] = sum_u x[ci,t,u]*att[n,s,u,v] -> Ypad ----------------
__global__ __launch_bounds__(128) void agg_kernel(const unsigned short* __restrict__ xbt,
                                                  const float* __restrict__ att,
                                                  unsigned short* __restrict__ ypad){
    __shared__ float attl[1875];
    __shared__ unsigned short vxl[3200];
    int bid = blockIdx.x; int n = bid >> 7; int t = bid & 127;
    int tid = threadIdx.x;  // = ci
    for (int i=tid; i<1875; i+=128) attl[i] = att[n*1875 + i];
    {
        const unsigned int* src = (const unsigned int*)(xbt + ((size_t)(n*3200 + t*25))*128);
        unsigned int* dst = (unsigned int*)vxl;
        for (int i=tid; i<1600; i+=128) dst[i] = src[i];
    }
    __syncthreads();
    float p[25];
    #pragma unroll
    for (int u2=0; u2<25; ++u2) p[u2] = bf2f(vxl[u2*128 + tid]);
    size_t obase = ((size_t)(n*3350 + 75 + t*25))*384 + tid;
    #pragma unroll
    for (int s=0; s<3; ++s){
        #pragma unroll 5
        for (int v2=0; v2<25; ++v2){
            float acc2 = 0.f;
            #pragma unroll
            for (int u2=0; u2<25; ++u2) acc2 += p[u2]*attl[s*625 + u2*25 + v2];
            ypad[obase + (size_t)v2*384 + s*128] = f2bf(acc2);
        }
    }
}

// ---------------- fused conv+ff GEMM (unchanged from R4) ----------------
__global__ __launch_bounds__(256,3) void gemm_fused(const unsigned short* __restrict__ Amat,
                                                    const unsigned short* __restrict__ Bsrc,
                                                    const float* __restrict__ xin,
                                                    const float* __restrict__ consts,
                                                    const unsigned short* __restrict__ ffA,
                                                    const float* __restrict__ wbpart,
                                                    const float* __restrict__ asum,
                                                    float* __restrict__ outf)
{
    constexpr int KTOT = 2688, NKB = 84;
    __shared__ unsigned short smem[24576];

    const int tid = threadIdx.x;
    const int bid = blockIdx.x;
    const int n   = bid/25;
    const int jn0 = (bid%25)*128;

    const int lane = tid & 63, wv = tid >> 6;
    const int wm = wv >> 1, wn = wv & 1;
    const int lr = lane & 15, lg = lane >> 4;
    const int swz = (lg ^ ((lr>>1)&3)) << 3;

    const int ga0 = tid, ga1 = 256 + tid;
    const int ra0 = ga0>>2, ra1 = ga1>>2;
    const int ca0 = ((ga0&3) ^ ((ra0>>1)&3))*8;
    const int ca1 = ((ga1&3) ^ ((ra1>>1)&3))*8;

    auto stage = [&](int kb, int buf){
        unsigned short* dst = smem + buf*8192;
        stage16(Amat + (size_t)ra0*KTOT + kb*32 + ca0, dst + ga0*8);
        stage16(Amat + (size_t)ra1*KTOT + kb*32 + ca1, dst + ga1*8);
        int k = kb%7, scb = (kb/7)*32;
        const unsigned short* bb = Bsrc + ((size_t)(n*3350 + jn0 + 25*k))*384 + scb;
        stage16(bb + (size_t)ra0*384 + ca0, dst + 4096 + ga0*8);
        stage16(bb + (size_t)ra1*384 + ca1, dst + 4096 + ga1*8);
    };

    f32x4 acc[4][4];
    #pragma unroll
    for (int a=0;a<4;a++)
        #pragma unroll
        for (int b=0;b<4;b++) acc[a][b] = (f32x4){0.f,0.f,0.f,0.f};

    stage(0, 0);
    stage(1, 1);
    int bufc = 0, bufp = 2;
    for (int kb=0; kb<NKB; ++kb){
        if (kb < NKB-1) asm volatile("s_waitcnt vmcnt(4)" ::: "memory");
        else            asm volatile("s_waitcnt vmcnt(0)" ::: "memory");
        __builtin_amdgcn_s_barrier();
        asm volatile("" ::: "memory");
        const unsigned short* sA = smem + bufc*8192;
        const unsigned short* sB = sA + 4096;
        s16x8 a[4], b[4];
        #pragma unroll
        for (int mf=0; mf<4; ++mf) a[mf] = *(const s16x8*)&sA[(wm*64+mf*16+lr)*32 + swz];
        #pragma unroll
        for (int nf=0; nf<4; ++nf) b[nf] = *(const s16x8*)&sB[(wn*64+nf*16+lr)*32 + swz];
        if (kb+2 < NKB) stage(kb+2, bufp);
        __builtin_amdgcn_s_setprio(1);
        #pragma unroll
        for (int mf=0; mf<4; ++mf)
            #pragma unroll
            for (int nf=0; nf<4; ++nf)
                acc[mf][nf] = __builtin_amdgcn_mfma_f32_16x16x32_bf16(a[mf], b[nf], acc[mf][nf], 0, 0, 0);
        __builtin_amdgcn_s_setprio(0);
        bufc = (bufc==2) ? 0 : bufc+1;
        bufp = (bufp==2) ? 0 : bufp+1;
    }
    __syncthreads();

    float* wbl = (float*)(smem + 17408);
    float* asl = wbl + 2688;
    for (int i=tid; i<2688; i+=256) wbl[i] = wbpart[i];
    for (int i=tid; i<75;   i+=256) asl[i] = asum[n*75 + i];
    __syncthreads();

    #pragma unroll
    for (int nf=0; nf<4; ++nf){
        int cj = wn*64 + nf*16 + lr;
        int j  = jn0 + cj;
        int t  = j/25, v = j - t*25;
        int tc = (t<3) ? t : ((t>124) ? (t-121) : 3);
        float a0 = asl[v], a1 = asl[25+v], a2 = asl[50+v];
        #pragma unroll
        for (int mf=0; mf<4; ++mf)
            #pragma unroll
            for (int r=0; r<4; ++r){
                int m = wm*64 + mf*16 + lg*4 + r;
                float b2v = wbl[m*21+tc]*a0 + wbl[m*21+7+tc]*a1 + wbl[m*21+14+tc]*a2;
                float val = acc[mf][nf][r]*consts[m] + consts[128+m] + b2v
                          + xin[(size_t)n*409600 + (size_t)m*3200 + j];
                val = (val >= 0.f) ? val : 0.1f*val;
                smem[cj*136 + m] = f2bf(val);
            }
    }
    __syncthreads();

    f32x4 acc2[4][4];
    #pragma unroll
    for (int a=0;a<4;a++)
        #pragma unroll
        for (int b=0;b<4;b++) acc2[a][b] = (f32x4){0.f,0.f,0.f,0.f};
    #pragma unroll
    for (int kb2=0; kb2<4; ++kb2){
        s16x8 a2[4], b2[4];
        #pragma unroll
        for (int mf=0; mf<4; ++mf)
            a2[mf] = *(const s16x8*)&ffA[(size_t)(wm*64+mf*16+lr)*128 + kb2*32 + lg*8];
        #pragma unroll
        for (int nf=0; nf<4; ++nf)
            b2[nf] = *(const s16x8*)&smem[(wn*64+nf*16+lr)*136 + kb2*32 + lg*8];
        #pragma unroll
        for (int mf=0; mf<4; ++mf)
            #pragma unroll
            for (int nf=0; nf<4; ++nf)
                acc2[mf][nf] = __builtin_amdgcn_mfma_f32_16x16x32_bf16(a2[mf], b2[nf], acc2[mf][nf], 0, 0, 0);
    }

    #pragma unroll
    for (int mf=0; mf<4; ++mf)
        #pragma unroll
        for (int r=0; r<4; ++r){
            int co = wm*64 + mf*16 + lg*4 + r;
            float sc2 = consts[256+co], bi2 = consts[384+co];
            #pragma unroll
            for (int nf=0; nf<4; ++nf){
                int cj = wn*64 + nf*16 + lr;
                size_t idx = (size_t)n*409600 + (size_t)co*3200 + jn0 + cj;
                float val = acc2[mf][nf][r]*sc2 + bi2 + xin[idx];
                val = (val >= 0.f) ? val : 0.1f*val;
                outf[idx] = val;
            }
        }
}

extern "C" void kernel_launch(void* const* d_in, const int* in_sizes, int n_in,
                              void* d_out, int out_size, void* d_ws, size_t ws_size,
                              hipStream_t stream) {
    const float* x      = (const float*)d_in[0];
    const float* theta  = (const float*)d_in[1];
    const float* atts   = (const float*)d_in[2];
    const float* alphas = (const float*)d_in[3];
    const float* v_w    = (const float*)d_in[4];
    const float* v_b    = (const float*)d_in[5];
    const float* out_w  = (const float*)d_in[6];
    const float* out_b  = (const float*)d_in[7];
    const float* out_g  = (const float*)d_in[8];
    const float* out_be = (const float*)d_in[9];
    const float* out_m  = (const float*)d_in[10];
    const float* out_v  = (const float*)d_in[11];
    const float* ff_w   = (const float*)d_in[12];
    const float* ff_b   = (const float*)d_in[13];
    const float* ff_g   = (const float*)d_in[14];
    const float* ff_be  = (const float*)d_in[15];
    const float* ff_m   = (const float*)d_in[16];
    const float* ff_v   = (const float*)d_in[17];
    float* out = (float*)d_out;

    char* w = (char*)d_ws;
    size_t off = 0;
    auto alloc = [&](size_t b){ size_t r = off; off += (b + 1023) & ~(size_t)1023; return r; };
    float*          G      = (float*)         (w + alloc(160000));      // 64*625 f32
    float*          attbuf = (float*)         (w + alloc(480000));      // 64*1875 f32
    float*          asumb  = (float*)         (w + alloc(19200));       // 64*75 f32
    float*          consts = (float*)         (w + alloc(2048));        // 512 f32
    float*          wbpart = (float*)         (w + alloc(10752));       // 128*21 f32
    float*          pebg   = (float*)         (w + alloc(12800));       // 25*128 f32
    float*          TPgb   = (float*)         (w + alloc(2500));        // 625 f32
    unsigned short* Wr     = (unsigned short*)(w + alloc(688128));      // 128*2688 bf16
    unsigned short* ffA    = (unsigned short*)(w + alloc(32768));
    unsigned short* xbt    = (unsigned short*)(w + alloc(52428800 + 16384)); // [n][jn][c] bf16 (+pad)
    unsigned short* ypad   = (unsigned short*)(w + alloc(164659200));   // [n][3350][384] bf16

    prep_kernel<<<2048,256,0,stream>>>(out_w, ff_w, v_b, out_b, out_g, out_be, out_m, out_v,
                                       ff_b, ff_g, ff_be, ff_m, ff_v,
                                       consts, ffA, ypad, wbpart, pebg, TPgb);
    wfold_kernel<<<896,384,0,stream>>>(out_w, v_w, Wr);
    xt_kernel<<<6400,256,0,stream>>>(x, xbt);
    gram_mfma<<<64,256,0,stream>>>(xbt, pebg, TPgb, G);
    attn_kernel<<<1,1024,0,stream>>>(G, theta, atts, alphas, attbuf, asumb);
    agg_kernel<<<8192,128,0,stream>>>(xbt, attbuf, ypad);
    gemm_fused<<<1600,256,0,stream>>>(Wr, ypad, x, consts, ffA, wbpart, asumb, out);
}

// Round 6
// 672.368 us; speedup vs baseline: 1.0581x; 1.0450x over previous
//
#include <hip/hip_runtime.h>
#include <hip/hip_bf16.h>
#include <math.h>

typedef __attribute__((ext_vector_type(8))) short s16x8;
typedef __attribute__((ext_vector_type(4))) float f32x4;

static __device__ __forceinline__ float bf2f(unsigned short u){
    unsigned int x = ((unsigned int)u) << 16; float f; __builtin_memcpy(&f,&x,4); return f;
}
static __device__ __forceinline__ unsigned short f2bf(float f){
    unsigned int x; __builtin_memcpy(&x,&f,4);
    unsigned int r = (x + 0x7FFFu + ((x>>16)&1u)) >> 16; return (unsigned short)r;
}

static __device__ __forceinline__ void stage16(const void* g, void* l){
    __builtin_amdgcn_global_load_lds((const __attribute__((address_space(1))) unsigned int*)g,
                                     (__attribute__((address_space(3))) unsigned int*)l, 16, 0, 0);
}

// ---------------- sizes ----------------
// N=64, C=128, T=128, V=25, S=3, K=7
// JN = 3200, NTV = 204800, PADROW = 3350, K-dim = 384*7 = 2688

// ---------------- prep: consts, ffA bf16, wbpart, peb, TPg, ypad halo zero ----------------
__global__ void prep_kernel(const float* __restrict__ out_w, const float* __restrict__ ff_w,
                            const float* __restrict__ v_b,
                            const float* __restrict__ out_b, const float* __restrict__ out_g,
                            const float* __restrict__ out_be, const float* __restrict__ out_m,
                            const float* __restrict__ out_v,
                            const float* __restrict__ ff_b, const float* __restrict__ ff_g,
                            const float* __restrict__ ff_be, const float* __restrict__ ff_m,
                            const float* __restrict__ ff_v,
                            float* __restrict__ consts,
                            unsigned short* __restrict__ ffA, unsigned short* __restrict__ ypad,
                            float* __restrict__ wbpart,
                            float* __restrict__ pebg, float* __restrict__ TPgb)
{
    int stride = gridDim.x*blockDim.x;
    int i0 = blockIdx.x*blockDim.x + threadIdx.x;
    const float KLN = 9.210340371976184f/128.f;   // ln(1e4)/C
    for (int i=i0; i<16384; i+=stride) ffA[i] = f2bf(ff_w[i]);
    for (int i=i0; i<128; i+=stride){
        float inv  = out_g[i]/sqrtf(out_v[i]+1e-5f);
        consts[i]       = inv;
        consts[128+i]   = out_b[i]*inv + out_be[i] - out_m[i]*inv;
        float invf = ff_g[i]/sqrtf(ff_v[i]+1e-5f);
        consts[256+i]   = invf;
        consts[384+i]   = ff_b[i]*invf + ff_be[i] - ff_m[i]*invf;
    }
    // pe table: pebg[v*128 + c]
    for (int i=i0; i<3200; i+=stride){
        int v = i >> 7, c = i & 127;
        float freq = expf(-(float)(c & ~1) * KLN);
        float ang = (float)v * freq;
        pebg[i] = (c & 1) ? cosf(ang) : sinf(ang);
    }
    // TPgb[u*25+v] = T * sum_c pe[c][u]*pe[c][v]
    for (int i=i0; i<625; i+=stride){
        int u = i/25, v = i%25;
        float acc = 0.f;
        for (int c=0; c<128; ++c){
            float freq = expf(-(float)(c & ~1) * KLN);
            float pu = (c & 1) ? cosf((float)u*freq) : sinf((float)u*freq);
            float pv = (c & 1) ? cosf((float)v*freq) : sinf((float)v*freq);
            acc += pu*pv;
        }
        TPgb[i] = 128.f*acc;
    }
    // wbpart[o][s][tc]
    for (int i=i0; i<2688; i+=stride){
        int o = i/21, rem = i%21, s = rem/7, tc = rem%7;
        int kmin = (tc<3) ? (3-tc) : 0;
        int kmax = (tc>3) ? (10-tc) : 7;
        float acc = 0.f;
        for (int c=0; c<128; ++c){
            const float* wp = out_w + (size_t)(o*384 + s*128 + c)*7;
            float vb = v_b[c];
            for (int k=kmin; k<kmax; ++k) acc += wp[k]*vb;
        }
        wbpart[i] = acc;
    }
    // zero the temporal halo pads of Ypad
    for (int i=i0; i<3686400; i+=stride){
        int n2 = i/57600, r2 = i%57600;
        int pp = r2/384, sc = r2%384;
        int ppos = (pp < 75) ? pp : (3200 + pp);
        ypad[(size_t)(n2*3350 + ppos)*384 + sc] = 0;
    }
}

// ---------------- wfold ----------------
__global__ __launch_bounds__(384) void wfold_kernel(const float* __restrict__ out_w,
                                                    const float* __restrict__ v_w,
                                                    unsigned short* __restrict__ Wr){
    __shared__ float owl[384];
    int o = blockIdx.x / 7, k = blockIdx.x % 7;
    int tid = threadIdx.x;
    owl[tid] = out_w[(size_t)(o*384 + tid)*7 + k];
    __syncthreads();
    int s = tid >> 7, ci = tid & 127;
    const float* ow = owl + s*128;
    float acc = 0.f;
    #pragma unroll 8
    for (int c=0; c<128; ++c) acc += ow[c] * v_w[c*128 + ci];
    int kb = (tid>>5)*7 + k, jj = tid & 31;
    Wr[(size_t)o*2688 + kb*32 + jj] = f2bf(acc);
}

// ---------------- x transpose + xbu emit ----------------
// xbt[n][jn][c] bf16 (for gram); xbu[n][t][c][32] bf16 u-padded (for agg_mfma; pads pre-zeroed)
__global__ __launch_bounds__(256) void xt_kernel(const float* __restrict__ x,
                                                 unsigned short* __restrict__ xbt,
                                                 unsigned short* __restrict__ xbu){
    __shared__ float tile[64][65];
    int bid = blockIdx.x;
    int jb = bid % 50; int cb = (bid/50) & 1; int n = bid/100;
    int lane = threadIdx.x & 63, wv = threadIdx.x >> 6;
    size_t xbase = (size_t)n*409600;
    int jn = jb*64 + lane;
    int tt = jn/25, uu = jn - tt*25;
    size_t xbu_lb = (size_t)n*524288 + (size_t)tt*4096 + uu;
    #pragma unroll
    for (int r=wv; r<64; r+=4){
        float v = x[xbase + (size_t)(cb*64+r)*3200 + jb*64 + lane];
        tile[r][lane] = v;
        xbu[xbu_lb + (size_t)(cb*64+r)*32] = f2bf(v);
    }
    __syncthreads();
    #pragma unroll
    for (int j=wv; j<64; j+=4)
        xbt[xbase + (size_t)(jb*64+j)*128 + cb*64 + lane] = f2bf(tile[lane][j]);
}

// ---------------- gram via MFMA (unchanged) ----------------
__global__ __launch_bounds__(256) void gram_mfma(const unsigned short* __restrict__ xbt,
                                                 const float* __restrict__ pebg,
                                                 const float* __restrict__ TPgb,
                                                 float* __restrict__ G){
    __shared__ float sxl[25][129];
    __shared__ float pebl[25][129];
    __shared__ float glx[4][32][32];
    int n = blockIdx.x, tid = threadIdx.x;
    const unsigned short* xb = xbt + (size_t)n*409600;

    int c = tid & 127, th = tid >> 7;
    float a[25];
    #pragma unroll
    for (int u=0; u<25; ++u) a[u] = 0.f;
    for (int tt=0; tt<64; ++tt){
        const unsigned short* row = xb + (size_t)(th*64+tt)*3200 + c;
        #pragma unroll
        for (int u=0; u<25; ++u) a[u] += bf2f(row[u*128]);
    }
    float* tmp = &glx[0][0][0];
    if (th){
        #pragma unroll
        for (int u=0; u<25; ++u) tmp[u*128+c] = a[u];
    }
    __syncthreads();
    if (!th){
        #pragma unroll
        for (int u=0; u<25; ++u) sxl[u][c] = a[u] + tmp[u*128+c];
    }
    for (int i=tid; i<3200; i+=256) pebl[i>>7][i&127] = pebg[i];
    __syncthreads();

    int lane = tid & 63, w = tid >> 6;
    int lr = lane & 15, lg = lane >> 4;
    f32x4 acc[2][2];
    #pragma unroll
    for (int i2=0;i2<2;i2++)
        #pragma unroll
        for (int j2=0;j2<2;j2++) acc[i2][j2] = (f32x4){0.f,0.f,0.f,0.f};
    for (int tt=0; tt<32; ++tt){
        int t = tt*4 + w;
        const unsigned short* tb = xb + (size_t)t*3200;
        #pragma unroll
        for (int kc=0; kc<4; ++kc){
            s16x8 f0 = *(const s16x8*)(tb + (size_t)(lr)*128      + kc*32 + lg*8);
            s16x8 f1 = *(const s16x8*)(tb + (size_t)(16+lr)*128   + kc*32 + lg*8);
            acc[0][0] = __builtin_amdgcn_mfma_f32_16x16x32_bf16(f0, f0, acc[0][0], 0,0,0);
            acc[0][1] = __builtin_amdgcn_mfma_f32_16x16x32_bf16(f0, f1, acc[0][1], 0,0,0);
            acc[1][0] = __builtin_amdgcn_mfma_f32_16x16x32_bf16(f1, f0, acc[1][0], 0,0,0);
            acc[1][1] = __builtin_amdgcn_mfma_f32_16x16x32_bf16(f1, f1, acc[1][1], 0,0,0);
        }
    }
    __syncthreads();
    #pragma unroll
    for (int mh=0; mh<2; ++mh)
        #pragma unroll
        for (int nh=0; nh<2; ++nh)
            #pragma unroll
            for (int r=0; r<4; ++r)
                glx[w][mh*16 + lg*4 + r][nh*16 + lr] = acc[mh][nh][r];
    __syncthreads();

    for (int idx=tid; idx<625; idx+=256){
        int u = idx/25, v = idx%25;
        float gx = glx[0][u][v] + glx[1][u][v] + glx[2][u][v] + glx[3][u][v];
        float cr = TPgb[idx];
        #pragma unroll 4
        for (int cc=0; cc<128; ++cc)
            cr += sxl[u][cc]*pebl[v][cc] + sxl[v][cc]*pebl[u][cc];
        G[n*625 + idx] = gx + cr;
    }
}

// ---------------- attention: global max + sparsemax -> att_pad bf16 [n][80][32] + asum ----------------
__global__ __launch_bounds__(1024) void attn_kernel(const float* __restrict__ G, const float* __restrict__ theta,
                                                    const float* __restrict__ atts, const float* __restrict__ alphas,
                                                    unsigned short* __restrict__ att_pad, float* __restrict__ asum){
    __shared__ float red[1024];
    int tid = threadIdx.x;
    float mx = 0.f;
    for (int idx=tid; idx<40000; idx+=1024){
        int n = idx/625, r = idx%625, u2 = r/25, v2 = r%25;
        const float* Gn = G + n*625;
        float d2v = fmaxf(Gn[u2*26] + Gn[v2*26] - 2.f*Gn[u2*25+v2], 0.f);
        mx = fmaxf(mx, d2v);
    }
    red[tid] = mx; __syncthreads();
    for (int s2=512; s2>0; s2>>=1){ if (tid < s2) red[tid] = fmaxf(red[tid], red[tid+s2]); __syncthreads(); }
    float inv = 1.f/red[0];
    // zero pad rows 75..79 of each n
    for (int i=tid; i<64*160; i+=1024){
        int n2 = i/160, r2 = i%160;
        att_pad[n2*2560 + 2400 + r2] = 0;
    }
    for (int col=tid; col<4800; col+=1024){
        int n = col/75, r = col%75, s = r/25, vc = r%25;
        const float* Gn = G + n*625;
        float et = expf(theta[s]);
        float al = alphas[s];
        float gvv = Gn[vc*26];
        float z[25];
        #pragma unroll
        for (int u2=0; u2<25; ++u2){
            float d2v = fmaxf(Gn[u2*26] + gvv - 2.f*Gn[u2*25+vc], 0.f);
            z[u2] = expf(-et*d2v*inv);
        }
        float zm = z[0];
        #pragma unroll
        for (int u2=1; u2<25; ++u2) zm = fmaxf(zm, z[u2]);
        float lo = zm - 1.f, hi = zm;
        for (int it=0; it<30; ++it){
            float mid = 0.5f*(lo+hi);
            float f = 0.f;
            #pragma unroll
            for (int u2=0; u2<25; ++u2) f += fmaxf(z[u2]-mid, 0.f);
            if (f >= 1.f) lo = mid; else hi = mid;
        }
        float ssum = 0.f; int kcnt = 0;
        #pragma unroll
        for (int u2=0; u2<25; ++u2){ if (z[u2] > lo){ ssum += z[u2]; kcnt++; } }
        float tau = (ssum - 1.f)/(float)kcnt;
        float as_ = 0.f;
        unsigned short* apr = att_pad + n*2560 + (s*25+vc)*32;
        #pragma unroll
        for (int u2=0; u2<25; ++u2){
            float av = atts[s*625 + u2*25 + vc] + fmaxf(z[u2]-tau, 0.f)*al;
            apr[u2] = f2bf(av);
            as_ += av;
        }
        #pragma unroll
        for (int u2=25; u2<32; ++u2) apr[u2] = 0;
        asum[n*75 + s*25 + vc] = as_;
    }
}

// ---------------- agg via MFMA: ypad[(n,t,v)][(s,ci)] = sum_u att[s,u,v] * x[ci,t,u] ----------------
// D[m=(s,v) 80][n=ci 128] per (n,t), K=32 (u padded); A=att_pad, B=xbu. No LDS.
__global__ __launch_bounds__(256,2) void agg_mfma(const unsigned short* __restrict__ att_pad,
                                                  const unsigned short* __restrict__ xbu,
                                                  unsigned short* __restrict__ ypad){
    int bid = blockIdx.x; int n = bid >> 4; int tb = bid & 15;
    int tid = threadIdx.x; int lane = tid & 63; int w = tid >> 6;
    int lr = lane & 15, lg = lane >> 4;
    const unsigned short* ap = att_pad + n*2560;
    s16x8 a[5];
    #pragma unroll
    for (int mf=0; mf<5; ++mf) a[mf] = *(const s16x8*)&ap[(mf*16+lr)*32 + lg*8];
    int rowoff[5][4];
    #pragma unroll
    for (int mf=0; mf<5; ++mf)
        #pragma unroll
        for (int r=0; r<4; ++r){
            int m = mf*16 + lg*4 + r;
            int s = m/25, v = m - s*25;
            rowoff[mf][r] = (m < 75) ? (v*384 + s*128 + lr) : -1;
        }
    #pragma unroll
    for (int ti=0; ti<2; ++ti){
        int t = tb*8 + w*2 + ti;
        const unsigned short* bp = xbu + (size_t)n*524288 + (size_t)t*4096;
        size_t obase = ((size_t)(n*3350 + 75 + t*25))*384;
        #pragma unroll
        for (int h=0; h<2; ++h){
            s16x8 b[4];
            #pragma unroll
            for (int q=0; q<4; ++q) b[q] = *(const s16x8*)&bp[(h*64 + q*16 + lr)*32 + lg*8];
            f32x4 acc[5][4];
            #pragma unroll
            for (int mf=0; mf<5; ++mf)
                #pragma unroll
                for (int q=0; q<4; ++q)
                    acc[mf][q] = (f32x4){0.f,0.f,0.f,0.f};
            #pragma unroll
            for (int mf=0; mf<5; ++mf)
                #pragma unroll
                for (int q=0; q<4; ++q)
                    acc[mf][q] = __builtin_amdgcn_mfma_f32_16x16x32_bf16(a[mf], b[q], acc[mf][q], 0, 0, 0);
            #pragma unroll
            for (int mf=0; mf<5; ++mf)
                #pragma unroll
                for (int q=0; q<4; ++q)
                    #pragma unroll
                    for (int r=0; r<4; ++r)
                        if (rowoff[mf][r] >= 0)
                            ypad[obase + rowoff[mf][r] + h*64 + q*16] = f2bf(acc[mf][q][r]);
        }
    }
}

// ---------------- fused conv+ff GEMM (unchanged) ----------------
__global__ __launch_bounds__(256,3) void gemm_fused(const unsigned short* __restrict__ Amat,
                                                    const unsigned short* __restrict__ Bsrc,
                                                    const float* __restrict__ xin,
                                                    const float* __restrict__ consts,
                                                    const unsigned short* __restrict__ ffA,
                                                    const float* __restrict__ wbpart,
                                                    const float* __restrict__ asum,
                                                    float* __restrict__ outf)
{
    constexpr int KTOT = 2688, NKB = 84;
    __shared__ unsigned short smem[24576];

    const int tid = threadIdx.x;
    const int bid = blockIdx.x;
    const int n   = bid/25;
    const int jn0 = (bid%25)*128;

    const int lane = tid & 63, wv = tid >> 6;
    const int wm = wv >> 1, wn = wv & 1;
    const int lr = lane & 15, lg = lane >> 4;
    const int swz = (lg ^ ((lr>>1)&3)) << 3;

    const int ga0 = tid, ga1 = 256 + tid;
    const int ra0 = ga0>>2, ra1 = ga1>>2;
    const int ca0 = ((ga0&3) ^ ((ra0>>1)&3))*8;
    const int ca1 = ((ga1&3) ^ ((ra1>>1)&3))*8;

    auto stage = [&](int kb, int buf){
        unsigned short* dst = smem + buf*8192;
        stage16(Amat + (size_t)ra0*KTOT + kb*32 + ca0, dst + ga0*8);
        stage16(Amat + (size_t)ra1*KTOT + kb*32 + ca1, dst + ga1*8);
        int k = kb%7, scb = (kb/7)*32;
        const unsigned short* bb = Bsrc + ((size_t)(n*3350 + jn0 + 25*k))*384 + scb;
        stage16(bb + (size_t)ra0*384 + ca0, dst + 4096 + ga0*8);
        stage16(bb + (size_t)ra1*384 + ca1, dst + 4096 + ga1*8);
    };

    f32x4 acc[4][4];
    #pragma unroll
    for (int a=0;a<4;a++)
        #pragma unroll
        for (int b=0;b<4;b++) acc[a][b] = (f32x4){0.f,0.f,0.f,0.f};

    stage(0, 0);
    stage(1, 1);
    int bufc = 0, bufp = 2;
    for (int kb=0; kb<NKB; ++kb){
        if (kb < NKB-1) asm volatile("s_waitcnt vmcnt(4)" ::: "memory");
        else            asm volatile("s_waitcnt vmcnt(0)" ::: "memory");
        __builtin_amdgcn_s_barrier();
        asm volatile("" ::: "memory");
        const unsigned short* sA = smem + bufc*8192;
        const unsigned short* sB = sA + 4096;
        s16x8 a[4], b[4];
        #pragma unroll
        for (int mf=0; mf<4; ++mf) a[mf] = *(const s16x8*)&sA[(wm*64+mf*16+lr)*32 + swz];
        #pragma unroll
        for (int nf=0; nf<4; ++nf) b[nf] = *(const s16x8*)&sB[(wn*64+nf*16+lr)*32 + swz];
        if (kb+2 < NKB) stage(kb+2, bufp);
        __builtin_amdgcn_s_setprio(1);
        #pragma unroll
        for (int mf=0; mf<4; ++mf)
            #pragma unroll
            for (int nf=0; nf<4; ++nf)
                acc[mf][nf] = __builtin_amdgcn_mfma_f32_16x16x32_bf16(a[mf], b[nf], acc[mf][nf], 0, 0, 0);
        __builtin_amdgcn_s_setprio(0);
        bufc = (bufc==2) ? 0 : bufc+1;
        bufp = (bufp==2) ? 0 : bufp+1;
    }
    __syncthreads();

    float* wbl = (float*)(smem + 17408);
    float* asl = wbl + 2688;
    for (int i=tid; i<2688; i+=256) wbl[i] = wbpart[i];
    for (int i=tid; i<75;   i+=256) asl[i] = asum[n*75 + i];
    __syncthreads();

    #pragma unroll
    for (int nf=0; nf<4; ++nf){
        int cj = wn*64 + nf*16 + lr;
        int j  = jn0 + cj;
        int t  = j/25, v = j - t*25;
        int tc = (t<3) ? t : ((t>124) ? (t-121) : 3);
        float a0 = asl[v], a1 = asl[25+v], a2 = asl[50+v];
        #pragma unroll
        for (int mf=0; mf<4; ++mf)
            #pragma unroll
            for (int r=0; r<4; ++r){
                int m = wm*64 + mf*16 + lg*4 + r;
                float b2v = wbl[m*21+tc]*a0 + wbl[m*21+7+tc]*a1 + wbl[m*21+14+tc]*a2;
                float val = acc[mf][nf][r]*consts[m] + consts[128+m] + b2v
                          + xin[(size_t)n*409600 + (size_t)m*3200 + j];
                val = (val >= 0.f) ? val : 0.1f*val;
                smem[cj*136 + m] = f2bf(val);
            }
    }
    __syncthreads();

    f32x4 acc2[4][4];
    #pragma unroll
    for (int a=0;a<4;a++)
        #pragma unroll
        for (int b=0;b<4;b++) acc2[a][b] = (f32x4){0.f,0.f,0.f,0.f};
    #pragma unroll
    for (int kb2=0; kb2<4; ++kb2){
        s16x8 a2[4], b2[4];
        #pragma unroll
        for (int mf=0; mf<4; ++mf)
            a2[mf] = *(const s16x8*)&ffA[(size_t)(wm*64+mf*16+lr)*128 + kb2*32 + lg*8];
        #pragma unroll
        for (int nf=0; nf<4; ++nf)
            b2[nf] = *(const s16x8*)&smem[(wn*64+nf*16+lr)*136 + kb2*32 + lg*8];
        #pragma unroll
        for (int mf=0; mf<4; ++mf)
            #pragma unroll
            for (int nf=0; nf<4; ++nf)
                acc2[mf][nf] = __builtin_amdgcn_mfma_f32_16x16x32_bf16(a2[mf], b2[nf], acc2[mf][nf], 0, 0, 0);
    }

    #pragma unroll
    for (int mf=0; mf<4; ++mf)
        #pragma unroll
        for (int r=0; r<4; ++r){
            int co = wm*64 + mf*16 + lg*4 + r;
            float sc2 = consts[256+co], bi2 = consts[384+co];
            #pragma unroll
            for (int nf=0; nf<4; ++nf){
                int cj = wn*64 + nf*16 + lr;
                size_t idx = (size_t)n*409600 + (size_t)co*3200 + jn0 + cj;
                float val = acc2[mf][nf][r]*sc2 + bi2 + xin[idx];
                val = (val >= 0.f) ? val : 0.1f*val;
                outf[idx] = val;
            }
        }
}

extern "C" void kernel_launch(void* const* d_in, const int* in_sizes, int n_in,
                              void* d_out, int out_size, void* d_ws, size_t ws_size,
                              hipStream_t stream) {
    const float* x      = (const float*)d_in[0];
    const float* theta  = (const float*)d_in[1];
    const float* atts   = (const float*)d_in[2];
    const float* alphas = (const float*)d_in[3];
    const float* v_w    = (const float*)d_in[4];
    const float* v_b    = (const float*)d_in[5];
    const float* out_w  = (const float*)d_in[6];
    const float* out_b  = (const float*)d_in[7];
    const float* out_g  = (const float*)d_in[8];
    const float* out_be = (const float*)d_in[9];
    const float* out_m  = (const float*)d_in[10];
    const float* out_v  = (const float*)d_in[11];
    const float* ff_w   = (const float*)d_in[12];
    const float* ff_b   = (const float*)d_in[13];
    const float* ff_g   = (const float*)d_in[14];
    const float* ff_be  = (const float*)d_in[15];
    const float* ff_m   = (const float*)d_in[16];
    const float* ff_v   = (const float*)d_in[17];
    float* out = (float*)d_out;

    char* w = (char*)d_ws;
    size_t off = 0;
    auto alloc = [&](size_t b){ size_t r = off; off += (b + 1023) & ~(size_t)1023; return r; };
    float*          G      = (float*)         (w + alloc(160000));      // 64*625 f32
    float*          asumb  = (float*)         (w + alloc(19200));       // 64*75 f32
    float*          consts = (float*)         (w + alloc(2048));        // 512 f32
    float*          wbpart = (float*)         (w + alloc(10752));       // 128*21 f32
    float*          pebg   = (float*)         (w + alloc(12800));       // 25*128 f32
    float*          TPgb   = (float*)         (w + alloc(2500));        // 625 f32
    float*          att_padf= nullptr; (void)att_padf;
    unsigned short* att_pad= (unsigned short*)(w + alloc(327680));      // 64*80*32 bf16
    unsigned short* Wr     = (unsigned short*)(w + alloc(688128));      // 128*2688 bf16
    unsigned short* ffA    = (unsigned short*)(w + alloc(32768));
    unsigned short* xbt    = (unsigned short*)(w + alloc(52428800 + 16384)); // [n][jn][c] bf16 (+pad)
    unsigned short* xbu    = (unsigned short*)(w + alloc(67108864));    // [n][t][c][32] bf16
    unsigned short* ypad   = (unsigned short*)(w + alloc(164659200));   // [n][3350][384] bf16

    hipMemsetAsync(xbu, 0, 67108864, stream);   // finite zeros in u-pads (incl. pre-poison call)
    prep_kernel<<<2048,256,0,stream>>>(out_w, ff_w, v_b, out_b, out_g, out_be, out_m, out_v,
                                       ff_b, ff_g, ff_be, ff_m, ff_v,
                                       consts, ffA, ypad, wbpart, pebg, TPgb);
    wfold_kernel<<<896,384,0,stream>>>(out_w, v_w, Wr);
    xt_kernel<<<6400,256,0,stream>>>(x, xbt, xbu);
    gram_mfma<<<64,256,0,stream>>>(xbt, pebg, TPgb, G);
    attn_kernel<<<1,1024,0,stream>>>(G, theta, atts, alphas, att_pad, asumb);
    agg_mfma<<<1024,256,0,stream>>>(att_pad, xbu, ypad);
    gemm_fused<<<1600,256,0,stream>>>(Wr, ypad, x, consts, ffA, wbpart, asumb, out);
}